// Round 1
// baseline (84.079 us; speedup 1.0000x reference)
//
#include <hip/hip_runtime.h>
#include <math.h>

// WaveNet with the torch-faithful truncation bug: skips are cut to the first
// 64 time steps (min over s.shape[0] == batch dim == 64). Only a ~96-wide
// prefix of each batch row of x is live. One block per batch, LDS window.

#define N_RES   20
#define N_L1    10     // layers 0..9  dilation 1, layers 10..19 dilation 2
#define W       96     // window width (need 85 at layer-0 input; 96 gives margin)
#define OUT_L   64     // truncated skip length (== batch size, the torch bug)

__global__ __launch_bounds__(128) void wavenet_window_kernel(
    const float* __restrict__ x,       // [64, 1, L]
    const float* __restrict__ cin_w,   // [2,1,1] -> [2]
    const float* __restrict__ cin_b,   // [2]
    const float* __restrict__ wd,      // [20,2,2,2]
    const float* __restrict__ bd,      // [20,2]
    const float* __restrict__ wg,      // [20,2,2,2]
    const float* __restrict__ bg,      // [20,2]
    const float* __restrict__ cout_w,  // [1,2,1] -> [2]
    const float* __restrict__ cout_b,  // [1]
    float* __restrict__ out,           // [64, 1, 64]
    int L)
{
    __shared__ float hbuf[2][2][W];    // [double-buffer][filter][pos]
    __shared__ float skip[2][OUT_L];   // [filter][pos]

    const int b   = blockIdx.x;
    const int tid = threadIdx.x;
    const float* xb = x + (size_t)b * (size_t)L;

    // conv_in (k=1): h[f][l] = cin_w[f]*x[l] + cin_b[f]
    for (int idx = tid; idx < 2 * W; idx += blockDim.x) {
        const int f = idx / W, l = idx % W;
        hbuf[0][f][l] = cin_w[f] * xb[l] + cin_b[f];
    }
    for (int idx = tid; idx < 2 * OUT_L; idx += blockDim.x) {
        skip[idx / OUT_L][idx % OUT_L] = 0.0f;
    }
    __syncthreads();

    int cur = 0;
    int valid = W;                      // h positions [0, valid) are correct
    for (int i = 0; i < N_RES; ++i) {
        const int d = (i < N_L1) ? 1 : 2;
        const float* wdi = wd + i * 8;  // [fo][fi][k] = wdi[fo*4 + fi*2 + k]
        const float* wgi = wg + i * 8;
        const float bd0 = bd[i * 2 + 0], bd1 = bd[i * 2 + 1];
        const float bg0 = bg[i * 2 + 0], bg1 = bg[i * 2 + 1];
        const int nout = valid - 1;     // compute positions [0, nout)

        for (int idx = tid; idx < 2 * W; idx += blockDim.x) {
            const int f = idx / W, l = idx % W;
            if (l < nout) {
                // taps: k=0 -> l - (d-1)  (zero-padded at -1 when d=2), k=1 -> l+1
                const int t0 = l - (d - 1);
                const float a0 = (t0 >= 0) ? hbuf[cur][0][t0] : 0.0f;
                const float a1 = (t0 >= 0) ? hbuf[cur][1][t0] : 0.0f;
                const float c0 = hbuf[cur][0][l + 1];
                const float c1 = hbuf[cur][1][l + 1];

                const float bdv = (f == 0) ? bd0 : bd1;
                const float bgv = (f == 0) ? bg0 : bg1;
                const float cd = wdi[f*4 + 0] * a0 + wdi[f*4 + 1] * c0
                               + wdi[f*4 + 2] * a1 + wdi[f*4 + 3] * c1 + bdv;
                const float cg = wgi[f*4 + 0] * a0 + wgi[f*4 + 1] * c0
                               + wgi[f*4 + 2] * a1 + wgi[f*4 + 3] * c1 + bgv;

                const float g = cd * (1.0f / (1.0f + expf(-cg)));
                // residual: d=1 -> h[l+1] + g (length shrinks by 1, left-trim),
                //           d=2 -> h[l]   + g (same length)
                const float hres = (d == 1) ? hbuf[cur][f][l + 1] : hbuf[cur][f][l];
                hbuf[1 - cur][f][l] = hres + g;
                if (l < OUT_L) skip[f][l] += g;
            }
        }
        __syncthreads();
        cur = 1 - cur;
        valid = nout;                   // window shrinks by 1 every layer
    }

    // conv_out (k=1) on relu(skip): out[b, 0, l]
    const float w0 = cout_w[0], w1 = cout_w[1], bo = cout_b[0];
    for (int l = tid; l < OUT_L; l += blockDim.x) {
        const float s0 = fmaxf(skip[0][l], 0.0f);
        const float s1 = fmaxf(skip[1][l], 0.0f);
        out[(size_t)b * OUT_L + l] = w0 * s0 + w1 * s1 + bo;
    }
}

extern "C" void kernel_launch(void* const* d_in, const int* in_sizes, int n_in,
                              void* d_out, int out_size, void* d_ws, size_t ws_size,
                              hipStream_t stream) {
    const float* x      = (const float*)d_in[0];
    const float* cin_w  = (const float*)d_in[1];
    const float* cin_b  = (const float*)d_in[2];
    const float* wd     = (const float*)d_in[3];
    const float* bd     = (const float*)d_in[4];
    const float* wg     = (const float*)d_in[5];
    const float* bg     = (const float*)d_in[6];
    const float* cout_w = (const float*)d_in[7];
    const float* cout_b = (const float*)d_in[8];
    float* out = (float*)d_out;

    const int B = 64;
    const int L = in_sizes[0] / B;      // 32768

    wavenet_window_kernel<<<B, 128, 0, stream>>>(
        x, cin_w, cin_b, wd, bd, wg, bg, cout_w, cout_b, out, L);
}

// Round 2
// 84.068 us; speedup vs baseline: 1.0001x; 1.0001x over previous
//
#include <hip/hip_runtime.h>
#include <math.h>

// WaveNet with the torch-faithful truncation bug: skips are cut to the first
// 64 time steps (min over s.shape[0] == batch dim == 64), so only a ~96-wide
// prefix of each batch row of x is live. One block (one wave) per batch,
// LDS double-buffered h-window, 20 recurrent gated layers, fused output conv.
//
// Round-2 note: rocprof shows the timed window is dominated by two 268 MB
// harness poison fills (~83 µs combined) — this kernel itself is a few µs.
// This version is the slimmed confirmation experiment (1 wave/block, shared
// taps for both filters, __expf).

#define N_RES   20
#define N_L1    10     // layers 0..9 dilation 1, layers 10..19 dilation 2
#define W       96     // window width (need 85 at layer-0 input)
#define OUT_L   64     // truncated skip length (== batch size, the torch bug)

__global__ __launch_bounds__(64) void wavenet_window_kernel(
    const float* __restrict__ x,       // [64, 1, L]
    const float* __restrict__ cin_w,   // [2]
    const float* __restrict__ cin_b,   // [2]
    const float* __restrict__ wd,      // [20,2,2,2]
    const float* __restrict__ bd,      // [20,2]
    const float* __restrict__ wg,      // [20,2,2,2]
    const float* __restrict__ bg,      // [20,2]
    const float* __restrict__ cout_w,  // [2]
    const float* __restrict__ cout_b,  // [1]
    float* __restrict__ out,           // [64, 1, 64]
    int L)
{
    __shared__ float hbuf[2][2][W];    // [double-buffer][filter][pos]
    __shared__ float skip[2][OUT_L];   // [filter][pos]

    const int b    = blockIdx.x;
    const int lane = threadIdx.x;      // 0..63, single wave
    const float* xb = x + (size_t)b * (size_t)L;

    // conv_in (k=1): h[f][l] = cin_w[f]*x[l] + cin_b[f]
    {
        const float cw0 = cin_w[0], cw1 = cin_w[1];
        const float cb0 = cin_b[0], cb1 = cin_b[1];
        const float xv = xb[lane];
        hbuf[0][0][lane] = cw0 * xv + cb0;
        hbuf[0][1][lane] = cw1 * xv + cb1;
        if (lane < W - 64) {
            const float xv2 = xb[lane + 64];
            hbuf[0][0][lane + 64] = cw0 * xv2 + cb0;
            hbuf[0][1][lane + 64] = cw1 * xv2 + cb1;
        }
        skip[0][lane] = 0.0f;
        skip[1][lane] = 0.0f;
    }
    __syncthreads();

    int cur = 0;
    int valid = W;                      // h positions [0, valid) are correct
    for (int i = 0; i < N_RES; ++i) {
        const int d = (i < N_L1) ? 1 : 2;
        const float* wdi = wd + i * 8;  // [fo][fi][k] = wdi[fo*4 + fi*2 + k]
        const float* wgi = wg + i * 8;
        const float wd00 = wdi[0], wd01 = wdi[1], wd02 = wdi[2], wd03 = wdi[3];
        const float wd10 = wdi[4], wd11 = wdi[5], wd12 = wdi[6], wd13 = wdi[7];
        const float wg00 = wgi[0], wg01 = wgi[1], wg02 = wgi[2], wg03 = wgi[3];
        const float wg10 = wgi[4], wg11 = wgi[5], wg12 = wgi[6], wg13 = wgi[7];
        const float bd0 = bd[i * 2 + 0], bd1 = bd[i * 2 + 1];
        const float bg0 = bg[i * 2 + 0], bg1 = bg[i * 2 + 1];
        const int nout = valid - 1;     // compute positions [0, nout)
        const int nxt  = 1 - cur;

        // positions 0..nout-1, two iterations of 64 lanes (nout <= 95)
        for (int l0 = 0; l0 < nout; l0 += 64) {
            const int l = l0 + lane;
            if (l < nout) {
                // taps: k=0 -> l-(d-1) (zero-padded at -1 when d=2), k=1 -> l+1
                const int t0 = l - (d - 1);
                const float a0 = (t0 >= 0) ? hbuf[cur][0][t0] : 0.0f;
                const float a1 = (t0 >= 0) ? hbuf[cur][1][t0] : 0.0f;
                const float c0 = hbuf[cur][0][l + 1];
                const float c1 = hbuf[cur][1][l + 1];

                const float cd_0 = wd00*a0 + wd01*c0 + wd02*a1 + wd03*c1 + bd0;
                const float cg_0 = wg00*a0 + wg01*c0 + wg02*a1 + wg03*c1 + bg0;
                const float cd_1 = wd10*a0 + wd11*c0 + wd12*a1 + wd13*c1 + bd1;
                const float cg_1 = wg10*a0 + wg11*c0 + wg12*a1 + wg13*c1 + bg1;

                const float g0 = cd_0 * (1.0f / (1.0f + __expf(-cg_0)));
                const float g1 = cd_1 * (1.0f / (1.0f + __expf(-cg_1)));

                // residual: d=1 -> h[l+1] + g (left-trim), d=2 -> h[l] + g
                const float hr0 = (d == 1) ? hbuf[cur][0][l + 1] : hbuf[cur][0][l];
                const float hr1 = (d == 1) ? hbuf[cur][1][l + 1] : hbuf[cur][1][l];
                hbuf[nxt][0][l] = hr0 + g0;
                hbuf[nxt][1][l] = hr1 + g1;
                if (l < OUT_L) {        // true only on the first iteration
                    skip[0][l] += g0;
                    skip[1][l] += g1;
                }
            }
        }
        __syncthreads();
        cur = nxt;
        valid = nout;                   // window shrinks by 1 every layer
    }

    // conv_out (k=1) on relu(skip): out[b, 0, l]
    const float w0 = cout_w[0], w1 = cout_w[1], bo = cout_b[0];
    const float s0 = fmaxf(skip[0][lane], 0.0f);
    const float s1 = fmaxf(skip[1][lane], 0.0f);
    out[(size_t)b * OUT_L + lane] = w0 * s0 + w1 * s1 + bo;
}

extern "C" void kernel_launch(void* const* d_in, const int* in_sizes, int n_in,
                              void* d_out, int out_size, void* d_ws, size_t ws_size,
                              hipStream_t stream) {
    const float* x      = (const float*)d_in[0];
    const float* cin_w  = (const float*)d_in[1];
    const float* cin_b  = (const float*)d_in[2];
    const float* wd     = (const float*)d_in[3];
    const float* bd     = (const float*)d_in[4];
    const float* wg     = (const float*)d_in[5];
    const float* bg     = (const float*)d_in[6];
    const float* cout_w = (const float*)d_in[7];
    const float* cout_b = (const float*)d_in[8];
    float* out = (float*)d_out;

    const int B = 64;
    const int L = in_sizes[0] / B;      // 32768

    wavenet_window_kernel<<<B, 64, 0, stream>>>(
        x, cin_w, cin_b, wd, bd, wg, bg, cout_w, cout_b, out, L);
}